// Round 3
// baseline (618.754 us; speedup 1.0000x reference)
//
#include <hip/hip_runtime.h>
#include <math.h>

#define MAXD 512   // per-node degree cap held in LDS (true max deg ~70 for this input)

__device__ __forceinline__ float lrelu(float v){ return v >= 0.f ? v : 0.2f * v; }

// ---------------- CSR build ----------------
__global__ void countK(const int* __restrict__ dstA, int E, int ET, int* __restrict__ deg){
  int e = blockIdx.x * blockDim.x + threadIdx.x;
  if (e >= ET) return;
  int d = (e < E) ? dstA[e] : (e - E);
  atomicAdd(&deg[d], 1);
}

__global__ void scanA(const int* __restrict__ deg, int* __restrict__ excl,
                      int* __restrict__ part, int n){
  __shared__ int s[256];
  int t = threadIdx.x;
  int i = blockIdx.x * 256 + t;
  int v = (i < n) ? deg[i] : 0;
  s[t] = v;
  __syncthreads();
  for (int o = 1; o < 256; o <<= 1){
    int tv = (t >= o) ? s[t - o] : 0;
    __syncthreads();
    s[t] += tv;
    __syncthreads();
  }
  if (i < n) excl[i] = s[t] - v;
  if (t == 255) part[blockIdx.x] = s[t];
}

__global__ void scanB(int* __restrict__ part, int nb){
  __shared__ int s[256];
  int t = threadIdx.x;
  int v = (t < nb) ? part[t] : 0;
  s[t] = v;
  __syncthreads();
  for (int o = 1; o < 256; o <<= 1){
    int tv = (t >= o) ? s[t - o] : 0;
    __syncthreads();
    s[t] += tv;
    __syncthreads();
  }
  if (t < nb) part[t] = s[t] - v;
}

__global__ void scanC(int* __restrict__ off, const int* __restrict__ part, int n, int ET){
  int i = blockIdx.x * 256 + threadIdx.x;
  if (i < n) off[i] += part[blockIdx.x];
  if (i == 0) off[n] = ET;
}

__global__ void scatterK(const int* __restrict__ srcA, const int* __restrict__ dstA, int E, int ET,
                         const int* __restrict__ off, int* __restrict__ cur, int* __restrict__ csrc){
  int e = blockIdx.x * blockDim.x + threadIdx.x;
  if (e >= ET) return;
  int s, d;
  if (e < E){ s = srcA[e]; d = dstA[e]; } else { s = e - E; d = s; }
  int p = off[d] + atomicAdd(&cur[d], 1);
  csrc[p] = s;
}

// ---------------- Layer 1: h1 = x@W1 fused with a_src/a_dst ----------------
// 4-node register blocking: each LDS weight read feeds 4 fmafs.
__global__ __launch_bounds__(256) void gemm1(const float* __restrict__ x, const float* __restrict__ W1,
    const float* __restrict__ attS, const float* __restrict__ attD,
    float* __restrict__ h1, float* __restrict__ a1s, float* __restrict__ a1d, int nN){
  __shared__ float Ws[128][64];
  int t = threadIdx.x;
  int half = blockIdx.y;                 // head (HID=64)
  for (int idx = t; idx < 128 * 64; idx += 256){
    int k = idx >> 6, c = idx & 63;
    Ws[k][c] = W1[k * 128 + half * 64 + c];
  }
  __syncthreads();
  int cl = t & 63, slot = t >> 6;
  float aS = attS[half * 64 + cl];
  float aD = attD[half * 64 + cl];
  int n0 = blockIdx.x * 16 + slot * 4;
  int m0 = min(n0 + 0, nN - 1), m1 = min(n0 + 1, nN - 1);
  int m2 = min(n0 + 2, nN - 1), m3 = min(n0 + 3, nN - 1);
  const float4* xr0 = reinterpret_cast<const float4*>(x + (size_t)m0 * 128);
  const float4* xr1 = reinterpret_cast<const float4*>(x + (size_t)m1 * 128);
  const float4* xr2 = reinterpret_cast<const float4*>(x + (size_t)m2 * 128);
  const float4* xr3 = reinterpret_cast<const float4*>(x + (size_t)m3 * 128);
  float A0 = 0.f, A1 = 0.f, A2 = 0.f, A3 = 0.f;
  #pragma unroll
  for (int k4 = 0; k4 < 32; ++k4){
    float4 x0 = xr0[k4], x1 = xr1[k4], x2 = xr2[k4], x3 = xr3[k4];
    float w0 = Ws[4 * k4 + 0][cl], w1 = Ws[4 * k4 + 1][cl];
    float w2 = Ws[4 * k4 + 2][cl], w3 = Ws[4 * k4 + 3][cl];
    A0 = fmaf(x0.x, w0, A0); A0 = fmaf(x0.y, w1, A0); A0 = fmaf(x0.z, w2, A0); A0 = fmaf(x0.w, w3, A0);
    A1 = fmaf(x1.x, w0, A1); A1 = fmaf(x1.y, w1, A1); A1 = fmaf(x1.z, w2, A1); A1 = fmaf(x1.w, w3, A1);
    A2 = fmaf(x2.x, w0, A2); A2 = fmaf(x2.y, w1, A2); A2 = fmaf(x2.z, w2, A2); A2 = fmaf(x2.w, w3, A2);
    A3 = fmaf(x3.x, w0, A3); A3 = fmaf(x3.y, w1, A3); A3 = fmaf(x3.z, w2, A3); A3 = fmaf(x3.w, w3, A3);
  }
  float Av[4] = {A0, A1, A2, A3};
  #pragma unroll
  for (int j = 0; j < 4; ++j){
    int n = n0 + j;
    if (n >= nN) break;
    h1[(size_t)n * 128 + half * 64 + cl] = Av[j];
    float ps = Av[j] * aS, pd = Av[j] * aD;
    #pragma unroll
    for (int o = 32; o > 0; o >>= 1){
      ps += __shfl_xor(ps, o);
      pd += __shfl_xor(pd, o);
    }
    if (cl == 0){
      a1s[n * 2 + half] = ps;
      a1d[n * 2 + half] = pd;
    }
  }
}

// ------- Layer 1 aggregation + fused (bias,ReLU, @W2, att2) per dst node -------
__global__ __launch_bounds__(128) void agg1(const int* __restrict__ off, const int* __restrict__ csrc,
    const float* __restrict__ a1s, const float* __restrict__ a1d,
    const float* __restrict__ h1, const float* __restrict__ b1,
    const float* __restrict__ W2, const float* __restrict__ attS2, const float* __restrict__ attD2,
    float* __restrict__ h2, float* __restrict__ a2s, float* __restrict__ a2d){
  __shared__ float al[MAXD][2];
  __shared__ int   sidx[MAXD];
  __shared__ float Ws2[128][9];          // +1 pad: conflict-free row reads
  __shared__ float wredm[2][2], wreds[2][2], wredv[2][8];
  int n = blockIdx.x, t = threadIdx.x;
  for (int idx = t; idx < 1024; idx += 128) Ws2[idx >> 3][idx & 7] = W2[idx];
  int start = off[n], end = off[n + 1];
  int deg = end - start;
  int degc = deg < MAXD ? deg : MAXD;
  float ad0 = a1d[2 * n], ad1 = a1d[2 * n + 1];
  // pass A: logits -> LDS, per-thread max
  float lm0 = -INFINITY, lm1 = -INFINITY;
  for (int i = t; i < degc; i += 128){
    int s = csrc[start + i];
    sidx[i] = s;
    float2 as = *reinterpret_cast<const float2*>(a1s + 2 * s);
    float l0 = lrelu(as.x + ad0), l1 = lrelu(as.y + ad1);
    al[i][0] = l0; al[i][1] = l1;
    lm0 = fmaxf(lm0, l0); lm1 = fmaxf(lm1, l1);
  }
  #pragma unroll
  for (int o = 32; o > 0; o >>= 1){
    lm0 = fmaxf(lm0, __shfl_xor(lm0, o));
    lm1 = fmaxf(lm1, __shfl_xor(lm1, o));
  }
  int wid = t >> 6, lane = t & 63;
  if (lane == 0){ wredm[wid][0] = lm0; wredm[wid][1] = lm1; }
  __syncthreads();
  float m0 = fmaxf(wredm[0][0], wredm[1][0]);
  float m1 = fmaxf(wredm[0][1], wredm[1][1]);
  // pass B: exp -> LDS, per-thread sum
  float ls0 = 0.f, ls1 = 0.f;
  for (int i = t; i < degc; i += 128){
    float e0 = expf(al[i][0] - m0), e1 = expf(al[i][1] - m1);
    al[i][0] = e0; al[i][1] = e1;
    ls0 += e0; ls1 += e1;
  }
  #pragma unroll
  for (int o = 32; o > 0; o >>= 1){
    ls0 += __shfl_xor(ls0, o);
    ls1 += __shfl_xor(ls1, o);
  }
  if (lane == 0){ wreds[wid][0] = ls0; wreds[wid][1] = ls1; }
  __syncthreads();
  float d0 = wreds[0][0] + wreds[1][0];
  float d1 = wreds[0][1] + wreds[1][1];
  // pass C: weighted gather of h1 rows (unroll 4 for MLP)
  int c = t, h = wid;
  float inv = 1.f / (h ? d1 : d0);
  float acc = 0.f;
  int i = 0;
  for (; i + 4 <= degc; i += 4){
    int s0 = sidx[i], s1 = sidx[i + 1], s2 = sidx[i + 2], s3 = sidx[i + 3];
    float w0 = al[i][h], w1 = al[i + 1][h], w2 = al[i + 2][h], w3 = al[i + 3][h];
    float v0 = h1[(size_t)s0 * 128 + c];
    float v1 = h1[(size_t)s1 * 128 + c];
    float v2 = h1[(size_t)s2 * 128 + c];
    float v3 = h1[(size_t)s3 * 128 + c];
    acc = fmaf(w0, v0, acc); acc = fmaf(w1, v1, acc);
    acc = fmaf(w2, v2, acc); acc = fmaf(w3, v3, acc);
  }
  for (; i < degc; ++i)
    acc = fmaf(al[i][h], h1[(size_t)sidx[i] * 128 + c], acc);
  float outc = fmaxf(fmaf(acc, inv, b1[c]), 0.f);   // out1 row element (relu'd), stays in reg
  // fused layer-2 GEMM (128 -> 8) + att2 reductions
  float p8[8];
  #pragma unroll
  for (int cc = 0; cc < 8; ++cc) p8[cc] = outc * Ws2[c][cc];
  #pragma unroll
  for (int o = 32; o > 0; o >>= 1){
    #pragma unroll
    for (int cc = 0; cc < 8; ++cc) p8[cc] += __shfl_xor(p8[cc], o);
  }
  if (lane == 0){
    #pragma unroll
    for (int cc = 0; cc < 8; ++cc) wredv[wid][cc] = p8[cc];
  }
  __syncthreads();
  if (t == 0){
    float s2v = 0.f, d2v = 0.f;
    #pragma unroll
    for (int cc = 0; cc < 8; ++cc){
      float hv = wredv[0][cc] + wredv[1][cc];
      h2[(size_t)n * 8 + cc] = hv;
      s2v = fmaf(hv, attS2[cc], s2v);
      d2v = fmaf(hv, attD2[cc], d2v);
    }
    a2s[n] = s2v; a2d[n] = d2v;
  }
}

// ---------------- Layer 2 aggregation (one wave per node) ----------------
__global__ __launch_bounds__(64) void agg2(const int* __restrict__ off, const int* __restrict__ csrc,
    const float* __restrict__ a2s, const float* __restrict__ a2d,
    const float* __restrict__ h2, const float* __restrict__ b2, float* __restrict__ out2){
  __shared__ float al[MAXD];
  __shared__ int sidx[MAXD];
  int n = blockIdx.x, t = threadIdx.x;
  int start = off[n], end = off[n + 1];
  int deg = end - start, degc = deg < MAXD ? deg : MAXD;
  float ad = a2d[n];
  float lm = -INFINITY;
  for (int i = t; i < degc; i += 64){
    int s = csrc[start + i];
    sidx[i] = s;
    float l = lrelu(a2s[s] + ad);
    al[i] = l;
    lm = fmaxf(lm, l);
  }
  #pragma unroll
  for (int o = 32; o > 0; o >>= 1) lm = fmaxf(lm, __shfl_xor(lm, o));
  float ls = 0.f;
  for (int i = t; i < degc; i += 64){
    float e = expf(al[i] - lm);   // same-lane entries only
    al[i] = e;
    ls += e;
  }
  #pragma unroll
  for (int o = 32; o > 0; o >>= 1) ls += __shfl_xor(ls, o);
  float dv = ls;
  __syncthreads();               // cross-lane al/sidx visibility for pass B
  int c = t & 7, sub = t >> 3;   // 8 edges in flight x 8 channels
  float acc = 0.f;
  int i = sub;
  for (; i + 16 <= degc; i += 16){
    float w0 = al[i], w1 = al[i + 8];
    float v0 = h2[(size_t)sidx[i] * 8 + c];
    float v1 = h2[(size_t)sidx[i + 8] * 8 + c];
    acc = fmaf(w0, v0, acc); acc = fmaf(w1, v1, acc);
  }
  for (; i < degc; i += 8) acc = fmaf(al[i], h2[(size_t)sidx[i] * 8 + c], acc);
  acc += __shfl_xor(acc, 8);
  acc += __shfl_xor(acc, 16);
  acc += __shfl_xor(acc, 32);
  if (t < 8) out2[(size_t)n * 8 + t] = fmaxf(acc / dv + b2[t], 0.f);
}

// ---------------- graph segment boundaries (batch is sorted) ----------------
__global__ void gsegK(const int* __restrict__ batch, int nN, int G, int* __restrict__ gstart){
  int g = blockIdx.x * blockDim.x + threadIdx.x;
  if (g > G) return;
  int lo = 0, hi = nN;
  while (lo < hi){
    int mid = (lo + hi) >> 1;
    if (batch[mid] < g) lo = mid + 1; else hi = mid;
  }
  gstart[g] = lo;
}

// ---------------- fused mean-pool + FC + sigmoid (no atomics) ----------------
__global__ __launch_bounds__(256) void poolFC(const float* __restrict__ out2,
    const int* __restrict__ gstart, const float* __restrict__ fcW,
    const float* __restrict__ fcb, float* __restrict__ out){
  __shared__ float red[256];
  int g = blockIdx.x;
  int s = gstart[g], e = gstart[g + 1];
  int t = threadIdx.x;
  int c = t & 7, row = t >> 3;
  float acc = 0.f;
  for (int i = s + row; i < e; i += 32) acc += out2[(size_t)i * 8 + c];
  red[t] = acc;
  __syncthreads();
  for (int o = 128; o >= 8; o >>= 1){
    if (t < o) red[t] += red[t + o];
    __syncthreads();
  }
  if (t == 0){
    float cc = fmaxf((float)(e - s), 1.0f);
    float y = fcb[0];
    #pragma unroll
    for (int c2 = 0; c2 < 8; ++c2) y += (red[c2] / cc) * fcW[c2];
    out[g] = 2.f / (1.f + expf(-y)) - 1.f;
  }
}

extern "C" void kernel_launch(void* const* d_in, const int* in_sizes, int n_in,
                              void* d_out, int out_size, void* d_ws, size_t ws_size,
                              hipStream_t stream){
  const float* x    = (const float*)d_in[0];
  const int*   ei   = (const int*)d_in[1];
  const int*   batch= (const int*)d_in[2];
  const float* W1   = (const float*)d_in[3];
  const float* aS1  = (const float*)d_in[4];
  const float* aD1  = (const float*)d_in[5];
  const float* b1   = (const float*)d_in[6];
  const float* W2   = (const float*)d_in[7];
  const float* aS2  = (const float*)d_in[8];
  const float* aD2  = (const float*)d_in[9];
  const float* b2   = (const float*)d_in[10];
  const float* fcW  = (const float*)d_in[11];
  const float* fcb  = (const float*)d_in[12];
  float* out = (float*)d_out;

  const int N  = in_sizes[0] / 128;
  const int E  = in_sizes[1] / 2;
  const int ET = E + N;
  const int G  = 64;

  const int* eiSrc = ei;
  const int* eiDst = ei + E;

  char* w = (char*)d_ws;
  size_t o = 0;
  auto alloc = [&](size_t bytes)->char*{
    o = (o + 255) & ~(size_t)255;
    char* p = w + o;
    o += bytes;
    return p;
  };
  int*   deg    = (int*)  alloc((size_t)N * 4);
  int*   cur    = (int*)  alloc((size_t)N * 4);
  size_t zbytes = (size_t)((char*)(cur + N) - (char*)deg);
  int*   csrOff = (int*)  alloc((size_t)(N + 1) * 4);
  int*   part   = (int*)  alloc(256 * 4);
  int*   gstart = (int*)  alloc((size_t)(G + 1) * 4);
  int*   csrc   = (int*)  alloc((size_t)ET * 4);
  float* h1     = (float*)alloc((size_t)N * 128 * 4);
  float* a1s    = (float*)alloc((size_t)N * 2 * 4);
  float* a1d    = (float*)alloc((size_t)N * 2 * 4);
  float* h2     = (float*)alloc((size_t)N * 8 * 4);
  float* a2s    = (float*)alloc((size_t)N * 4);
  float* a2d    = (float*)alloc((size_t)N * 4);
  float* out2   = (float*)alloc((size_t)N * 8 * 4);
  (void)ws_size; (void)n_in; (void)out_size;

  hipMemsetAsync(deg, 0, zbytes, stream);

  int ebl = (ET + 255) / 256;
  int nbl = (N + 255) / 256;

  countK  <<<ebl, 256, 0, stream>>>(eiDst, E, ET, deg);
  scanA   <<<nbl, 256, 0, stream>>>(deg, csrOff, part, N);
  scanB   <<<1,   256, 0, stream>>>(part, nbl);
  scanC   <<<nbl, 256, 0, stream>>>(csrOff, part, N, ET);
  scatterK<<<ebl, 256, 0, stream>>>(eiSrc, eiDst, E, ET, csrOff, cur, csrc);
  gsegK   <<<1, 128, 0, stream>>>(batch, N, G, gstart);

  dim3 g1((N + 15) / 16, 2);
  gemm1<<<g1, 256, 0, stream>>>(x, W1, aS1, aD1, h1, a1s, a1d, N);
  agg1 <<<N, 128, 0, stream>>>(csrOff, csrc, a1s, a1d, h1, b1, W2, aS2, aD2, h2, a2s, a2d);
  agg2 <<<N, 64, 0, stream>>>(csrOff, csrc, a2s, a2d, h2, b2, out2);
  poolFC<<<G, 256, 0, stream>>>(out2, gstart, fcW, fcb, out);
}

// Round 4
// 463.797 us; speedup vs baseline: 1.3341x; 1.3341x over previous
//
#include <hip/hip_runtime.h>
#include <math.h>

#define MAXD 512   // per-node degree cap held in LDS (true max deg ~70 for this input)

__device__ __forceinline__ float lrelu(float v){ return v >= 0.f ? v : 0.2f * v; }

// ---------------- CSR build ----------------
__global__ void countK(const int* __restrict__ dstA, int E, int ET, int* __restrict__ deg){
  int e = blockIdx.x * blockDim.x + threadIdx.x;
  if (e >= ET) return;
  int d = (e < E) ? dstA[e] : (e - E);
  atomicAdd(&deg[d], 1);
}

__global__ void scanA(const int* __restrict__ deg, int* __restrict__ excl,
                      int* __restrict__ part, int n){
  __shared__ int s[256];
  int t = threadIdx.x;
  int i = blockIdx.x * 256 + t;
  int v = (i < n) ? deg[i] : 0;
  s[t] = v;
  __syncthreads();
  for (int o = 1; o < 256; o <<= 1){
    int tv = (t >= o) ? s[t - o] : 0;
    __syncthreads();
    s[t] += tv;
    __syncthreads();
  }
  if (i < n) excl[i] = s[t] - v;
  if (t == 255) part[blockIdx.x] = s[t];
}

__global__ void scanB(int* __restrict__ part, int nb){
  __shared__ int s[256];
  int t = threadIdx.x;
  int v = (t < nb) ? part[t] : 0;
  s[t] = v;
  __syncthreads();
  for (int o = 1; o < 256; o <<= 1){
    int tv = (t >= o) ? s[t - o] : 0;
    __syncthreads();
    s[t] += tv;
    __syncthreads();
  }
  if (t < nb) part[t] = s[t] - v;
}

__global__ void scanC(int* __restrict__ off, const int* __restrict__ part, int n, int ET){
  int i = blockIdx.x * 256 + threadIdx.x;
  if (i < n) off[i] += part[blockIdx.x];
  if (i == 0) off[n] = ET;
}

__global__ void scatterK(const int* __restrict__ srcA, const int* __restrict__ dstA, int E, int ET,
                         const int* __restrict__ off, int* __restrict__ cur, int* __restrict__ csrc){
  int e = blockIdx.x * blockDim.x + threadIdx.x;
  if (e >= ET) return;
  int s, d;
  if (e < E){ s = srcA[e]; d = dstA[e]; } else { s = e - E; d = s; }
  int p = off[d] + atomicAdd(&cur[d], 1);
  csrc[p] = s;
}

// ---------------- Layer 1: h1 = x@W1 fused with a_src/a_dst ----------------
// 4-node register blocking; launch_bounds caps VGPR<=128 (4 waves/SIMD),
// unroll 4 keeps the load window small (R3's full unroll hit 256 VGPR, 8% occ).
__global__ __launch_bounds__(256, 4) void gemm1(const float* __restrict__ x, const float* __restrict__ W1,
    const float* __restrict__ attS, const float* __restrict__ attD,
    float* __restrict__ h1, float* __restrict__ a1s, float* __restrict__ a1d, int nN){
  __shared__ float Ws[128][64];
  int t = threadIdx.x;
  int half = blockIdx.y;                 // head (HID=64)
  for (int idx = t; idx < 128 * 64; idx += 256){
    int k = idx >> 6, c = idx & 63;
    Ws[k][c] = W1[k * 128 + half * 64 + c];
  }
  __syncthreads();
  int cl = t & 63, slot = t >> 6;
  float aS = attS[half * 64 + cl];
  float aD = attD[half * 64 + cl];
  int n0 = blockIdx.x * 16 + slot * 4;
  int m0 = min(n0 + 0, nN - 1), m1 = min(n0 + 1, nN - 1);
  int m2 = min(n0 + 2, nN - 1), m3 = min(n0 + 3, nN - 1);
  const float4* xr0 = reinterpret_cast<const float4*>(x + (size_t)m0 * 128);
  const float4* xr1 = reinterpret_cast<const float4*>(x + (size_t)m1 * 128);
  const float4* xr2 = reinterpret_cast<const float4*>(x + (size_t)m2 * 128);
  const float4* xr3 = reinterpret_cast<const float4*>(x + (size_t)m3 * 128);
  float A0 = 0.f, A1 = 0.f, A2 = 0.f, A3 = 0.f;
  #pragma unroll 4
  for (int k4 = 0; k4 < 32; ++k4){
    float4 x0 = xr0[k4], x1 = xr1[k4], x2 = xr2[k4], x3 = xr3[k4];
    float w0 = Ws[4 * k4 + 0][cl], w1 = Ws[4 * k4 + 1][cl];
    float w2 = Ws[4 * k4 + 2][cl], w3 = Ws[4 * k4 + 3][cl];
    A0 = fmaf(x0.x, w0, A0); A0 = fmaf(x0.y, w1, A0); A0 = fmaf(x0.z, w2, A0); A0 = fmaf(x0.w, w3, A0);
    A1 = fmaf(x1.x, w0, A1); A1 = fmaf(x1.y, w1, A1); A1 = fmaf(x1.z, w2, A1); A1 = fmaf(x1.w, w3, A1);
    A2 = fmaf(x2.x, w0, A2); A2 = fmaf(x2.y, w1, A2); A2 = fmaf(x2.z, w2, A2); A2 = fmaf(x2.w, w3, A2);
    A3 = fmaf(x3.x, w0, A3); A3 = fmaf(x3.y, w1, A3); A3 = fmaf(x3.z, w2, A3); A3 = fmaf(x3.w, w3, A3);
  }
  float Av[4] = {A0, A1, A2, A3};
  #pragma unroll
  for (int j = 0; j < 4; ++j){
    int n = n0 + j;
    if (n >= nN) break;
    h1[(size_t)n * 128 + half * 64 + cl] = Av[j];
    float ps = Av[j] * aS, pd = Av[j] * aD;
    #pragma unroll
    for (int o = 32; o > 0; o >>= 1){
      ps += __shfl_xor(ps, o);
      pd += __shfl_xor(pd, o);
    }
    if (cl == 0){
      a1s[n * 2 + half] = ps;
      a1d[n * 2 + half] = pd;
    }
  }
}

// ------- Layer 1 aggregation + fused (bias,ReLU, @W2, att2) per dst node -------
__global__ __launch_bounds__(128) void agg1(const int* __restrict__ off, const int* __restrict__ csrc,
    const float* __restrict__ a1s, const float* __restrict__ a1d,
    const float* __restrict__ h1, const float* __restrict__ b1,
    const float* __restrict__ W2, const float* __restrict__ attS2, const float* __restrict__ attD2,
    float* __restrict__ h2, float* __restrict__ a2s, float* __restrict__ a2d){
  __shared__ float al[MAXD][2];
  __shared__ int   sidx[MAXD];
  __shared__ float Ws2[128][9];          // +1 pad: conflict-free row reads
  __shared__ float wredm[2][2], wreds[2][2], wredv[2][8];
  int n = blockIdx.x, t = threadIdx.x;
  for (int idx = t; idx < 1024; idx += 128) Ws2[idx >> 3][idx & 7] = W2[idx];
  int start = off[n], end = off[n + 1];
  int deg = end - start;
  int degc = deg < MAXD ? deg : MAXD;
  float ad0 = a1d[2 * n], ad1 = a1d[2 * n + 1];
  // pass A: logits -> LDS, per-thread max
  float lm0 = -INFINITY, lm1 = -INFINITY;
  for (int i = t; i < degc; i += 128){
    int s = csrc[start + i];
    sidx[i] = s;
    float2 as = *reinterpret_cast<const float2*>(a1s + 2 * s);
    float l0 = lrelu(as.x + ad0), l1 = lrelu(as.y + ad1);
    al[i][0] = l0; al[i][1] = l1;
    lm0 = fmaxf(lm0, l0); lm1 = fmaxf(lm1, l1);
  }
  #pragma unroll
  for (int o = 32; o > 0; o >>= 1){
    lm0 = fmaxf(lm0, __shfl_xor(lm0, o));
    lm1 = fmaxf(lm1, __shfl_xor(lm1, o));
  }
  int wid = t >> 6, lane = t & 63;
  if (lane == 0){ wredm[wid][0] = lm0; wredm[wid][1] = lm1; }
  __syncthreads();
  float m0 = fmaxf(wredm[0][0], wredm[1][0]);
  float m1 = fmaxf(wredm[0][1], wredm[1][1]);
  // pass B: exp -> LDS, per-thread sum
  float ls0 = 0.f, ls1 = 0.f;
  for (int i = t; i < degc; i += 128){
    float e0 = expf(al[i][0] - m0), e1 = expf(al[i][1] - m1);
    al[i][0] = e0; al[i][1] = e1;
    ls0 += e0; ls1 += e1;
  }
  #pragma unroll
  for (int o = 32; o > 0; o >>= 1){
    ls0 += __shfl_xor(ls0, o);
    ls1 += __shfl_xor(ls1, o);
  }
  if (lane == 0){ wreds[wid][0] = ls0; wreds[wid][1] = ls1; }
  __syncthreads();
  float d0 = wreds[0][0] + wreds[1][0];
  float d1 = wreds[0][1] + wreds[1][1];
  // pass C: weighted gather of h1 rows (unroll 4 for MLP)
  int c = t, h = wid;
  float inv = 1.f / (h ? d1 : d0);
  float acc = 0.f;
  int i = 0;
  for (; i + 4 <= degc; i += 4){
    int s0 = sidx[i], s1 = sidx[i + 1], s2 = sidx[i + 2], s3 = sidx[i + 3];
    float w0 = al[i][h], w1 = al[i + 1][h], w2 = al[i + 2][h], w3 = al[i + 3][h];
    float v0 = h1[(size_t)s0 * 128 + c];
    float v1 = h1[(size_t)s1 * 128 + c];
    float v2 = h1[(size_t)s2 * 128 + c];
    float v3 = h1[(size_t)s3 * 128 + c];
    acc = fmaf(w0, v0, acc); acc = fmaf(w1, v1, acc);
    acc = fmaf(w2, v2, acc); acc = fmaf(w3, v3, acc);
  }
  for (; i < degc; ++i)
    acc = fmaf(al[i][h], h1[(size_t)sidx[i] * 128 + c], acc);
  float outc = fmaxf(fmaf(acc, inv, b1[c]), 0.f);   // out1 row element (relu'd), stays in reg
  // fused layer-2 GEMM (128 -> 8) + att2 reductions
  float p8[8];
  #pragma unroll
  for (int cc = 0; cc < 8; ++cc) p8[cc] = outc * Ws2[c][cc];
  #pragma unroll
  for (int o = 32; o > 0; o >>= 1){
    #pragma unroll
    for (int cc = 0; cc < 8; ++cc) p8[cc] += __shfl_xor(p8[cc], o);
  }
  if (lane == 0){
    #pragma unroll
    for (int cc = 0; cc < 8; ++cc) wredv[wid][cc] = p8[cc];
  }
  __syncthreads();
  if (t == 0){
    float s2v = 0.f, d2v = 0.f;
    #pragma unroll
    for (int cc = 0; cc < 8; ++cc){
      float hv = wredv[0][cc] + wredv[1][cc];
      h2[(size_t)n * 8 + cc] = hv;
      s2v = fmaf(hv, attS2[cc], s2v);
      d2v = fmaf(hv, attD2[cc], d2v);
    }
    a2s[n] = s2v; a2d[n] = d2v;
  }
}

// ---------------- Layer 2 aggregation (one wave per node) ----------------
__global__ __launch_bounds__(64) void agg2(const int* __restrict__ off, const int* __restrict__ csrc,
    const float* __restrict__ a2s, const float* __restrict__ a2d,
    const float* __restrict__ h2, const float* __restrict__ b2, float* __restrict__ out2){
  __shared__ float al[MAXD];
  __shared__ int sidx[MAXD];
  int n = blockIdx.x, t = threadIdx.x;
  int start = off[n], end = off[n + 1];
  int deg = end - start, degc = deg < MAXD ? deg : MAXD;
  float ad = a2d[n];
  float lm = -INFINITY;
  for (int i = t; i < degc; i += 64){
    int s = csrc[start + i];
    sidx[i] = s;
    float l = lrelu(a2s[s] + ad);
    al[i] = l;
    lm = fmaxf(lm, l);
  }
  #pragma unroll
  for (int o = 32; o > 0; o >>= 1) lm = fmaxf(lm, __shfl_xor(lm, o));
  float ls = 0.f;
  for (int i = t; i < degc; i += 64){
    float e = expf(al[i] - lm);   // same-lane entries only
    al[i] = e;
    ls += e;
  }
  #pragma unroll
  for (int o = 32; o > 0; o >>= 1) ls += __shfl_xor(ls, o);
  float dv = ls;
  __syncthreads();               // cross-lane al/sidx visibility for pass B
  int c = t & 7, sub = t >> 3;   // 8 edges in flight x 8 channels
  float acc = 0.f;
  int i = sub;
  for (; i + 16 <= degc; i += 16){
    float w0 = al[i], w1 = al[i + 8];
    float v0 = h2[(size_t)sidx[i] * 8 + c];
    float v1 = h2[(size_t)sidx[i + 8] * 8 + c];
    acc = fmaf(w0, v0, acc); acc = fmaf(w1, v1, acc);
  }
  for (; i < degc; i += 8) acc = fmaf(al[i], h2[(size_t)sidx[i] * 8 + c], acc);
  acc += __shfl_xor(acc, 8);
  acc += __shfl_xor(acc, 16);
  acc += __shfl_xor(acc, 32);
  if (t < 8) out2[(size_t)n * 8 + t] = fmaxf(acc / dv + b2[t], 0.f);
}

// ---------------- graph segment boundaries (batch is sorted) ----------------
__global__ void gsegK(const int* __restrict__ batch, int nN, int G, int* __restrict__ gstart){
  int g = blockIdx.x * blockDim.x + threadIdx.x;
  if (g > G) return;
  int lo = 0, hi = nN;
  while (lo < hi){
    int mid = (lo + hi) >> 1;
    if (batch[mid] < g) lo = mid + 1; else hi = mid;
  }
  gstart[g] = lo;
}

// ---------------- fused mean-pool + FC + sigmoid (no atomics) ----------------
__global__ __launch_bounds__(256) void poolFC(const float* __restrict__ out2,
    const int* __restrict__ gstart, const float* __restrict__ fcW,
    const float* __restrict__ fcb, float* __restrict__ out){
  __shared__ float red[256];
  int g = blockIdx.x;
  int s = gstart[g], e = gstart[g + 1];
  int t = threadIdx.x;
  int c = t & 7, row = t >> 3;
  float acc = 0.f;
  for (int i = s + row; i < e; i += 32) acc += out2[(size_t)i * 8 + c];
  red[t] = acc;
  __syncthreads();
  for (int o = 128; o >= 8; o >>= 1){
    if (t < o) red[t] += red[t + o];
    __syncthreads();
  }
  if (t == 0){
    float cc = fmaxf((float)(e - s), 1.0f);
    float y = fcb[0];
    #pragma unroll
    for (int c2 = 0; c2 < 8; ++c2) y += (red[c2] / cc) * fcW[c2];
    out[g] = 2.f / (1.f + expf(-y)) - 1.f;
  }
}

extern "C" void kernel_launch(void* const* d_in, const int* in_sizes, int n_in,
                              void* d_out, int out_size, void* d_ws, size_t ws_size,
                              hipStream_t stream){
  const float* x    = (const float*)d_in[0];
  const int*   ei   = (const int*)d_in[1];
  const int*   batch= (const int*)d_in[2];
  const float* W1   = (const float*)d_in[3];
  const float* aS1  = (const float*)d_in[4];
  const float* aD1  = (const float*)d_in[5];
  const float* b1   = (const float*)d_in[6];
  const float* W2   = (const float*)d_in[7];
  const float* aS2  = (const float*)d_in[8];
  const float* aD2  = (const float*)d_in[9];
  const float* b2   = (const float*)d_in[10];
  const float* fcW  = (const float*)d_in[11];
  const float* fcb  = (const float*)d_in[12];
  float* out = (float*)d_out;

  const int N  = in_sizes[0] / 128;
  const int E  = in_sizes[1] / 2;
  const int ET = E + N;
  const int G  = 64;

  const int* eiSrc = ei;
  const int* eiDst = ei + E;

  char* w = (char*)d_ws;
  size_t o = 0;
  auto alloc = [&](size_t bytes)->char*{
    o = (o + 255) & ~(size_t)255;
    char* p = w + o;
    o += bytes;
    return p;
  };
  int*   deg    = (int*)  alloc((size_t)N * 4);
  int*   cur    = (int*)  alloc((size_t)N * 4);
  size_t zbytes = (size_t)((char*)(cur + N) - (char*)deg);
  int*   csrOff = (int*)  alloc((size_t)(N + 1) * 4);
  int*   part   = (int*)  alloc(256 * 4);
  int*   gstart = (int*)  alloc((size_t)(G + 1) * 4);
  int*   csrc   = (int*)  alloc((size_t)ET * 4);
  float* h1     = (float*)alloc((size_t)N * 128 * 4);
  float* a1s    = (float*)alloc((size_t)N * 2 * 4);
  float* a1d    = (float*)alloc((size_t)N * 2 * 4);
  float* h2     = (float*)alloc((size_t)N * 8 * 4);
  float* a2s    = (float*)alloc((size_t)N * 4);
  float* a2d    = (float*)alloc((size_t)N * 4);
  float* out2   = (float*)alloc((size_t)N * 8 * 4);
  (void)ws_size; (void)n_in; (void)out_size;

  hipMemsetAsync(deg, 0, zbytes, stream);

  int ebl = (ET + 255) / 256;
  int nbl = (N + 255) / 256;

  countK  <<<ebl, 256, 0, stream>>>(eiDst, E, ET, deg);
  scanA   <<<nbl, 256, 0, stream>>>(deg, csrOff, part, N);
  scanB   <<<1,   256, 0, stream>>>(part, nbl);
  scanC   <<<nbl, 256, 0, stream>>>(csrOff, part, N, ET);
  scatterK<<<ebl, 256, 0, stream>>>(eiSrc, eiDst, E, ET, csrOff, cur, csrc);
  gsegK   <<<1, 128, 0, stream>>>(batch, N, G, gstart);

  dim3 g1((N + 15) / 16, 2);
  gemm1<<<g1, 256, 0, stream>>>(x, W1, aS1, aD1, h1, a1s, a1d, N);
  agg1 <<<N, 128, 0, stream>>>(csrOff, csrc, a1s, a1d, h1, b1, W2, aS2, aD2, h2, a2s, a2d);
  agg2 <<<N, 64, 0, stream>>>(csrOff, csrc, a2s, a2d, h2, b2, out2);
  poolFC<<<G, 256, 0, stream>>>(out2, gstart, fcW, fcb, out);
}